// Round 4
// baseline (278.123 us; speedup 1.0000x reference)
//
#include <hip/hip_runtime.h>
#include <hip/hip_bf16.h>
#include <math.h>

#define NROWS 32768
#define DD    1024
#define EE    640
#define VV    320
#define BM    32
#define KT    32      // DD/32
#define CTN   40      // EE/16

typedef __attribute__((ext_vector_type(8))) short short8;
typedef __attribute__((ext_vector_type(4))) float float4v;

static __device__ __forceinline__ unsigned short f2bf(float f) {
    unsigned int u = __float_as_uint(f);
    return (unsigned short)((u + 0x7fffu + ((u >> 16) & 1u)) >> 16); // RNE
}

// hardware cvt: 8 fp32 -> 8 bf16 (v_cvt_pk_bf16_f32, RNE)
static __device__ __forceinline__ short8 cvt8(float4 a, float4 b) {
    float2 f0 = {a.x, a.y}, f1 = {a.z, a.w}, f2 = {b.x, b.y}, f3 = {b.z, b.w};
    union { __hip_bfloat162 h[4]; short8 s; } u;
    u.h[0] = __float22bfloat162_rn(f0);
    u.h[1] = __float22bfloat162_rn(f1);
    u.h[2] = __float22bfloat162_rn(f2);
    u.h[3] = __float22bfloat162_rn(f3);
    return u.s;
}

// Pack W [K=1024][N=640] fp32 -> bf16, MFMA fragment layout:
// frag(kt, ct): lane l, elem e  <=  W[kt*32 + (l>>4)*8 + e][ct*16 + (l&15)]
__global__ void pack_w(const float* __restrict__ W, unsigned short* __restrict__ bp)
{
    const int t = threadIdx.x;
    const int tile = blockIdx.x * 4 + (t >> 6);   // 0..1279 = kt*40+ct
    const int lane = t & 63;
    const int kt = tile / CTN, ct = tile % CTN;
    const int k0 = kt * 32 + (lane >> 4) * 8;
    const int col = ct * 16 + (lane & 15);
    unsigned short v1[8];
    #pragma unroll
    for (int e = 0; e < 8; ++e)
        v1[e] = f2bf(W[(size_t)(k0 + e) * EE + col]);
    *(short8*)(bp + ((size_t)tile * 64 + lane) * 8) = *(const short8*)v1;
}

// 1024 blocks x 256 threads. Block: 32 rows x all 640 cols.
// Wave w = cg: cols cg*160..+159 (10 frags), rows 0..31 (rf 0,1). acc[2][10].
// NO LDS / NO barriers in the main loop: A direct from global (L1-shared
// across the 4 waves), B direct from the packed L2-resident fragment buffer.
__global__ __launch_bounds__(256, 3) void fused_mfma(
    const float* __restrict__ x, const unsigned short* __restrict__ bp,
    const float* __restrict__ bias, const float* __restrict__ cb,
    const float* __restrict__ gum, float* __restrict__ out,
    float* __restrict__ probs_acc)
{
    __shared__ float probs_blk[EE];
    __shared__ float pmax[4][BM];
    __shared__ float psum[4][BM];
    __shared__ int   pidx[4][BM];
    __shared__ int   fidx[BM][2];
    __shared__ float finv[BM][2];

    const int t    = threadIdx.x;
    const int lane = t & 63;
    const int cg   = t >> 6;            // wave id = col group
    const int n0   = blockIdx.x * BM;

    float4v acc[2][10];
    #pragma unroll
    for (int rf = 0; rf < 2; ++rf)
        #pragma unroll
        for (int ct = 0; ct < 10; ++ct)
            acc[rf][ct] = (float4v)0.f;

    // A addressing: lane l, elem e <= x[n0 + rf*16 + (l&15)][kt*32 + (l>>4)*8 + e]
    const float* xl = x + (size_t)(n0 + (lane & 15)) * DD + (lane >> 4) * 8;
    // B addressing: frag (kt, cg*10+ct), this lane's 8 elems
    const unsigned short* bpw = bp + ((size_t)cg * 10 * 64 + lane) * 8;

    float4 acur[2][2], anxt[2][2];
    #pragma unroll
    for (int rf = 0; rf < 2; ++rf) {
        acur[rf][0] = *(const float4*)(xl + (size_t)rf * 16 * DD);
        acur[rf][1] = *(const float4*)(xl + (size_t)rf * 16 * DD + 4);
    }

    for (int kt = 0; kt < KT; ++kt) {
        if (kt + 1 < KT) {
            const float* xn = xl + (kt + 1) * 32;
            #pragma unroll
            for (int rf = 0; rf < 2; ++rf) {
                anxt[rf][0] = *(const float4*)(xn + (size_t)rf * 16 * DD);
                anxt[rf][1] = *(const float4*)(xn + (size_t)rf * 16 * DD + 4);
            }
        }
        short8 af[2];
        #pragma unroll
        for (int rf = 0; rf < 2; ++rf)
            af[rf] = cvt8(acur[rf][0], acur[rf][1]);

        const unsigned short* bk = bpw + (size_t)kt * (CTN * 64 * 8);
        #pragma unroll
        for (int ct = 0; ct < 10; ++ct) {
            short8 bf = *(const short8*)(bk + ct * 512);
            #pragma unroll
            for (int rf = 0; rf < 2; ++rf)
                acc[rf][ct] = __builtin_amdgcn_mfma_f32_16x16x32_bf16(af[rf], bf, acc[rf][ct], 0, 0, 0);
        }
        #pragma unroll
        for (int rf = 0; rf < 2; ++rf) {
            acur[rf][0] = anxt[rf][0];
            acur[rf][1] = anxt[rf][1];
        }
    }

    // bias (zeros in this problem; kept faithful)
    {
        float bv[10];
        #pragma unroll
        for (int ct = 0; ct < 10; ++ct) bv[ct] = bias[cg*160 + ct*16 + (lane & 15)];
        #pragma unroll
        for (int rf = 0; rf < 2; ++rf)
            #pragma unroll
            for (int ct = 0; ct < 10; ++ct) {
                acc[rf][ct][0] += bv[ct]; acc[rf][ct][1] += bv[ct];
                acc[rf][ct][2] += bv[ct]; acc[rf][ct][3] += bv[ct];
            }
    }

    // ---- Phase A: gumbel-argmax partial + clean exp-sum partial ----
    const int g = cg >> 1;
    const int goff0 = (cg & 1)*160 + (lane & 15);
    #pragma unroll
    for (int rf = 0; rf < 2; ++rf) {
        #pragma unroll
        for (int r = 0; r < 4; ++r) {
            const int rowA = rf*16 + ((lane >> 4) << 2) + r;
            const float* grow = gum + ((size_t)(n0 + rowA)*2 + g)*VV + goff0;
            float m1 = -1e30f; int bi = 0; float es = 0.f;
            #pragma unroll
            for (int ct = 0; ct < 10; ++ct) {
                float z  = acc[rf][ct][r];
                float zg = z + grow[ct*16];
                if (zg > m1) { m1 = zg; bi = goff0 + ct*16; }
                es += __expf(z);
            }
            #pragma unroll
            for (int off = 1; off < 16; off <<= 1) {
                float om = __shfl_xor(m1, off);
                int   ob = __shfl_xor(bi, off);
                if (om > m1 || (om == m1 && ob < bi)) { m1 = om; bi = ob; }
                es += __shfl_xor(es, off);
            }
            if ((lane & 15) == 0) {
                pmax[cg][rowA] = m1; pidx[cg][rowA] = bi; psum[cg][rowA] = es;
            }
        }
    }
    for (int c = t; c < EE; c += 256) probs_blk[c] = 0.f;
    __syncthreads();

    // ---- Phase B: cross-wave combine (waves 2g, 2g+1 per group) ----
    if (t < 64) {
        const int row = t & 31, gg = t >> 5;
        const float mA = pmax[gg*2][row], mB = pmax[gg*2+1][row];
        const int   iA = pidx[gg*2][row], iB = pidx[gg*2+1][row];
        fidx[row][gg] = (mB > mA || (mB == mA && iB < iA)) ? iB : iA;
        finv[row][gg] = 1.f / (psum[gg*2][row] + psum[gg*2+1][row]);
    }
    __syncthreads();

    // ---- Phase C: probs accumulation ----
    float pacc[10];
    #pragma unroll
    for (int ct = 0; ct < 10; ++ct) pacc[ct] = 0.f;
    #pragma unroll
    for (int rf = 0; rf < 2; ++rf) {
        #pragma unroll
        for (int r = 0; r < 4; ++r) {
            const int rowA = rf*16 + ((lane >> 4) << 2) + r;
            const float inv = finv[rowA][g];
            #pragma unroll
            for (int ct = 0; ct < 10; ++ct)
                pacc[ct] += __expf(acc[rf][ct][r]) * inv;
        }
    }
    #pragma unroll
    for (int off = 16; off < 64; off <<= 1)
        #pragma unroll
        for (int ct = 0; ct < 10; ++ct)
            pacc[ct] += __shfl_xor(pacc[ct], off);
    if (lane < 16) {
        #pragma unroll
        for (int ct = 0; ct < 10; ++ct)
            atomicAdd(&probs_blk[cg*160 + ct*16 + lane], pacc[ct]);
    }
    __syncthreads();

    for (int c = t; c < EE; c += 256)
        atomicAdd(&probs_acc[c], probs_blk[c]);

    // ---- output: codebook gather (row-uniform idx, coalesced 4KB/iter) ----
    #pragma unroll 4
    for (int j = 0; j < BM; ++j) {
        const int gg  = t >> 7;
        const int idx = fidx[j][gg];
        const float4 v = *(const float4*)&cb[((size_t)gg*VV + idx)*512 + (size_t)(t & 127)*4];
        *(float4*)&out[(size_t)(n0 + j)*DD + (size_t)t*4] = v;
    }
}

__global__ void perp_kernel(const float* __restrict__ probs_acc,
                            float* __restrict__ outp)
{
    __shared__ float s0[4], s1[4];
    int t = threadIdx.x;   // 256
    float p0 = 0.f, p1 = 0.f;
    for (int c = t; c < EE; c += 256) {
        float a = probs_acc[c] * (1.0f / NROWS);
        float v = a * logf(a + 1e-7f);
        if (c < VV) p0 += v; else p1 += v;
    }
    #pragma unroll
    for (int off = 1; off < 64; off <<= 1) {
        p0 += __shfl_xor(p0, off);
        p1 += __shfl_xor(p1, off);
    }
    if ((t & 63) == 0) { s0[t >> 6] = p0; s1[t >> 6] = p1; }
    __syncthreads();
    if (t == 0) {
        float a0 = s0[0] + s0[1] + s0[2] + s0[3];
        float a1 = s1[0] + s1[1] + s1[2] + s1[3];
        outp[0] = 0.5f * (expf(-a0) + expf(-a1));
    }
}

extern "C" void kernel_launch(void* const* d_in, const int* in_sizes, int n_in,
                              void* d_out, int out_size, void* d_ws, size_t ws_size,
                              hipStream_t stream)
{
    const float* x   = (const float*)d_in[0];
    const float* W   = (const float*)d_in[1];
    const float* b   = (const float*)d_in[2];
    const float* cb  = (const float*)d_in[3];
    const float* gum = (const float*)d_in[4];
    float* out = (float*)d_out;

    unsigned short* bp = (unsigned short*)d_ws;                  // 1.31 MB packed W
    float* probs_acc = (float*)((char*)d_ws + (size_t)DD*EE*2);

    hipMemsetAsync(probs_acc, 0, EE * sizeof(float), stream);
    pack_w<<<320, 256, 0, stream>>>(W, bp);
    fused_mfma<<<NROWS / BM, 256, 0, stream>>>(x, bp, b, cb, gum, out, probs_acc);
    perp_kernel<<<1, 256, 0, stream>>>(probs_acc, out + (out_size - 1));
}

// Round 5
// 131.003 us; speedup vs baseline: 2.1230x; 2.1230x over previous
//
#include <hip/hip_runtime.h>
#include <hip/hip_bf16.h>
#include <math.h>

#define NROWS 32768
#define DD    1024
#define EE    640
#define VV    320
#define BM    64
#define KT    32      // DD/32
#define CTN   40      // EE/16

typedef __attribute__((ext_vector_type(8))) short short8;
typedef __attribute__((ext_vector_type(4))) short short4v;
typedef __attribute__((ext_vector_type(4))) float float4v;

static __device__ __forceinline__ unsigned short f2bf(float f) {
    unsigned int u = __float_as_uint(f);
    return (unsigned short)((u + 0x7fffu + ((u >> 16) & 1u)) >> 16); // RNE
}

static __device__ __forceinline__ void gload_lds16(const void* g, void* l) {
    __builtin_amdgcn_global_load_lds(
        (const __attribute__((address_space(1))) unsigned int*)g,
        (__attribute__((address_space(3))) unsigned int*)l, 16, 0, 0);
}

// Pack W [K=1024][N=640] fp32 -> bf16, MFMA fragment layout:
// frag(kt, ct): lane l, elem e  <=  W[kt*32 + (l>>4)*8 + e][ct*16 + (l&15)]
__global__ void pack_w(const float* __restrict__ W, unsigned short* __restrict__ bp)
{
    const int t = threadIdx.x;
    const int tile = blockIdx.x * 4 + (t >> 6);   // 0..1279 = kt*40+ct
    const int lane = t & 63;
    const int kt = tile / CTN, ct = tile % CTN;
    const int k0 = kt * 32 + (lane >> 4) * 8;
    const int col = ct * 16 + (lane & 15);
    unsigned short v1[8];
    #pragma unroll
    for (int e = 0; e < 8; ++e)
        v1[e] = f2bf(W[(size_t)(k0 + e) * EE + col]);
    *(short8*)(bp + ((size_t)tile * 64 + lane) * 8) = *(const short8*)v1;
}

// 512 blocks x 512 threads (= 2 blocks/CU). Block: 64 rows x all 640 cols.
// Wave w=cg (0..7): ALL 64 rows (rf 0..3), cols cg*80..+79 (5 frags). acc[4][5].
__global__ __launch_bounds__(512, 4) void fused_mfma(
    const float* __restrict__ x, const unsigned short* __restrict__ bp,
    const float* __restrict__ bias, const float* __restrict__ cb,
    const float* __restrict__ gum, float* __restrict__ out,
    float* __restrict__ probs_acc)
{
    __shared__ unsigned short Bs[32 * EE];        // 40 KB, single buffer
    __shared__ unsigned short As[BM * 32];        // 4 KB, single buffer
    __shared__ float probs_blk[EE];
    __shared__ float pmax[8][BM];
    __shared__ float psum[8][BM];
    __shared__ int   pidx[8][BM];
    __shared__ int   fidx[BM][2];
    __shared__ float finv[BM][2];

    const int t    = threadIdx.x;
    const int lane = t & 63;
    const int cg   = t >> 6;            // wave id = col group (80 cols)
    const int n0   = blockIdx.x * BM;

    float4v acc[4][5];
    #pragma unroll
    for (int rf = 0; rf < 4; ++rf)
        #pragma unroll
        for (int ct = 0; ct < 5; ++ct)
            acc[rf][ct] = (float4v)0.f;

    // A staging: thread t stages one float4: row r = t>>3, k-quad kq = t&7
    const int r0 = t >> 3, kq0 = t & 7;
    const int abase = (r0 >> 4)*512 + ((r0 & 15) + ((kq0 >> 1) << 4))*8 + ((kq0 & 1) << 2);
    const float* xr = x + (size_t)(n0 + r0) * DD + kq0 * 4;

    auto writeA = [&](float4 v) {
        short4v s1;
        s1[0] = (short)f2bf(v.x); s1[1] = (short)f2bf(v.y);
        s1[2] = (short)f2bf(v.z); s1[3] = (short)f2bf(v.w);
        *(short4v*)&As[abase] = s1;
    };
    // B staging: 2560 16B-slots per kt; thread t stages slots s*512+t
    auto stageB = [&](int kt) {
        const unsigned short* src = bp + (size_t)kt * (32 * EE);
        #pragma unroll
        for (int s = 0; s < 5; ++s) {
            const int q = s * 512 + t;
            gload_lds16(src + (size_t)q * 8, &Bs[q * 8]);
        }
    };

    // prologue
    float4 pA = *(const float4*)(xr);
    stageB(0);
    __syncthreads();          // drain: pA landed, Bs staged
    writeA(pA);
    __syncthreads();

    for (int kt = 0; kt < KT; ++kt) {
        const bool more = (kt + 1 < KT);
        if (more) pA = *(const float4*)(xr + (kt + 1) * 32);   // issue-early

        short8 af[4];
        #pragma unroll
        for (int rf = 0; rf < 4; ++rf)
            af[rf] = *(const short8*)&As[rf*512 + lane*8];
        #pragma unroll
        for (int ct = 0; ct < 5; ++ct) {
            short8 bf = *(const short8*)&Bs[((cg*5 + ct)*64 + lane)*8];
            #pragma unroll
            for (int rf = 0; rf < 4; ++rf)
                acc[rf][ct] = __builtin_amdgcn_mfma_f32_16x16x32_bf16(af[rf], bf, acc[rf][ct], 0, 0, 0);
        }
        __syncthreads();      // #1: all reads of As/Bs done (drains pA too)
        if (more) {
            stageB(kt + 1);   // async into Bs (safe post-barrier)
            writeA(pA);
        }
        __syncthreads();      // #2: staging complete (vmcnt/lgkm drained)
    }

    // bias (zeros in this problem; kept faithful)
    {
        float bv[5];
        #pragma unroll
        for (int ct = 0; ct < 5; ++ct) bv[ct] = bias[cg*80 + ct*16 + (lane & 15)];
        #pragma unroll
        for (int rf = 0; rf < 4; ++rf)
            #pragma unroll
            for (int ct = 0; ct < 5; ++ct) {
                acc[rf][ct][0] += bv[ct]; acc[rf][ct][1] += bv[ct];
                acc[rf][ct][2] += bv[ct]; acc[rf][ct][3] += bv[ct];
            }
    }

    // ---- Phase A: gumbel-argmax partial + clean exp-sum partial ----
    const int g = cg >> 2;                         // 4 waves per group
    const int goff0 = (cg & 3)*80 + (lane & 15);   // col within group
    #pragma unroll
    for (int rf = 0; rf < 4; ++rf) {
        #pragma unroll
        for (int r = 0; r < 4; ++r) {
            const int rowA = rf*16 + ((lane >> 4) << 2) + r;
            const float* grow = gum + ((size_t)(n0 + rowA)*2 + g)*VV + goff0;
            float m1 = -1e30f; int bi = 0; float es = 0.f;
            #pragma unroll
            for (int ct = 0; ct < 5; ++ct) {
                float z  = acc[rf][ct][r];
                float zg = z + grow[ct*16];
                if (zg > m1) { m1 = zg; bi = goff0 + ct*16; }
                es += __expf(z);
            }
            #pragma unroll
            for (int off = 1; off < 16; off <<= 1) {
                float om = __shfl_xor(m1, off);
                int   ob = __shfl_xor(bi, off);
                if (om > m1 || (om == m1 && ob < bi)) { m1 = om; bi = ob; }
                es += __shfl_xor(es, off);
            }
            if ((lane & 15) == 0) {
                pmax[cg][rowA] = m1; pidx[cg][rowA] = bi; psum[cg][rowA] = es;
            }
        }
    }
    for (int c = t; c < EE; c += 512) probs_blk[c] = 0.f;
    __syncthreads();

    // ---- Phase B: cross-wave combine (4 partials per row,group) ----
    if (t < 128) {
        const int row = t & 63, gg = t >> 6;
        float m1 = -1e30f; int bi = 0x7fffffff; float s = 0.f;
        #pragma unroll
        for (int c = 0; c < 4; ++c) {
            const float om = pmax[gg*4 + c][row];
            const int   ob = pidx[gg*4 + c][row];
            if (om > m1 || (om == m1 && ob < bi)) { m1 = om; bi = ob; }
            s += psum[gg*4 + c][row];
        }
        fidx[row][gg] = bi;
        finv[row][gg] = 1.f / s;
    }
    __syncthreads();

    // ---- Phase C: probs accumulation ----
    float pacc[5];
    #pragma unroll
    for (int ct = 0; ct < 5; ++ct) pacc[ct] = 0.f;
    #pragma unroll
    for (int rf = 0; rf < 4; ++rf) {
        #pragma unroll
        for (int r = 0; r < 4; ++r) {
            const int rowA = rf*16 + ((lane >> 4) << 2) + r;
            const float inv = finv[rowA][g];
            #pragma unroll
            for (int ct = 0; ct < 5; ++ct)
                pacc[ct] += __expf(acc[rf][ct][r]) * inv;
        }
    }
    #pragma unroll
    for (int off = 16; off < 64; off <<= 1)
        #pragma unroll
        for (int ct = 0; ct < 5; ++ct)
            pacc[ct] += __shfl_xor(pacc[ct], off);
    if (lane < 16) {
        #pragma unroll
        for (int ct = 0; ct < 5; ++ct)
            atomicAdd(&probs_blk[cg*80 + ct*16 + lane], pacc[ct]);
    }
    __syncthreads();

    for (int c = t; c < EE; c += 512)
        atomicAdd(&probs_acc[c], probs_blk[c]);

    // ---- output: codebook gather (row-uniform idx, coalesced) ----
    for (int i = t; i < BM*256; i += 512) {
        const int row = i >> 8, f4 = i & 255;
        const int gg  = f4 >> 7;
        const int idx = fidx[row][gg];
        const float4 v = *(const float4*)&cb[((size_t)gg*VV + idx)*512 + (size_t)(f4 & 127)*4];
        *(float4*)&out[(size_t)(n0 + row)*DD + (size_t)f4*4] = v;
    }
}

__global__ void perp_kernel(const float* __restrict__ probs_acc,
                            float* __restrict__ outp)
{
    __shared__ float s0[4], s1[4];
    int t = threadIdx.x;   // 256
    float p0 = 0.f, p1 = 0.f;
    for (int c = t; c < EE; c += 256) {
        float a = probs_acc[c] * (1.0f / NROWS);
        float v = a * logf(a + 1e-7f);
        if (c < VV) p0 += v; else p1 += v;
    }
    #pragma unroll
    for (int off = 1; off < 64; off <<= 1) {
        p0 += __shfl_xor(p0, off);
        p1 += __shfl_xor(p1, off);
    }
    if ((t & 63) == 0) { s0[t >> 6] = p0; s1[t >> 6] = p1; }
    __syncthreads();
    if (t == 0) {
        float a0 = s0[0] + s0[1] + s0[2] + s0[3];
        float a1 = s1[0] + s1[1] + s1[2] + s1[3];
        outp[0] = 0.5f * (expf(-a0) + expf(-a1));
    }
}

extern "C" void kernel_launch(void* const* d_in, const int* in_sizes, int n_in,
                              void* d_out, int out_size, void* d_ws, size_t ws_size,
                              hipStream_t stream)
{
    const float* x   = (const float*)d_in[0];
    const float* W   = (const float*)d_in[1];
    const float* b   = (const float*)d_in[2];
    const float* cb  = (const float*)d_in[3];
    const float* gum = (const float*)d_in[4];
    float* out = (float*)d_out;

    unsigned short* bp = (unsigned short*)d_ws;                  // 1.31 MB packed W
    float* probs_acc = (float*)((char*)d_ws + (size_t)DD*EE*2);

    hipMemsetAsync(probs_acc, 0, EE * sizeof(float), stream);
    pack_w<<<320, 256, 0, stream>>>(W, bp);
    fused_mfma<<<NROWS / BM, 512, 0, stream>>>(x, bp, b, cb, gum, out, probs_acc);
    perp_kernel<<<1, 256, 0, stream>>>(probs_acc, out + (out_size - 1));
}

// Round 6
// 130.608 us; speedup vs baseline: 2.1294x; 1.0030x over previous
//
#include <hip/hip_runtime.h>
#include <hip/hip_bf16.h>
#include <math.h>

#define NROWS 32768
#define DD    1024
#define EE    640
#define VV    320
#define BM    128
#define KT    32      // DD/32
#define CTN   40      // EE/16

typedef __attribute__((ext_vector_type(8))) short short8;
typedef __attribute__((ext_vector_type(4))) short short4v;
typedef __attribute__((ext_vector_type(4))) float float4v;

static __device__ __forceinline__ unsigned short f2bf(float f) {
    unsigned int u = __float_as_uint(f);
    return (unsigned short)((u + 0x7fffu + ((u >> 16) & 1u)) >> 16); // RNE
}

static __device__ __forceinline__ void gload_lds16(const void* g, void* l) {
    __builtin_amdgcn_global_load_lds(
        (const __attribute__((address_space(1))) unsigned int*)g,
        (__attribute__((address_space(3))) unsigned int*)l, 16, 0, 0);
}

// Pack W [K=1024][N=640] fp32 -> bf16, MFMA fragment layout:
// frag(kt, ct): lane l, elem e  <=  W[kt*32 + (l>>4)*8 + e][ct*16 + (l&15)]
__global__ void pack_w(const float* __restrict__ W, unsigned short* __restrict__ bp)
{
    const int t = threadIdx.x;
    const int tile = blockIdx.x * 4 + (t >> 6);   // 0..1279 = kt*40+ct
    const int lane = t & 63;
    const int kt = tile / CTN, ct = tile % CTN;
    const int k0 = kt * 32 + (lane >> 4) * 8;
    const int col = ct * 16 + (lane & 15);
    unsigned short v1[8];
    #pragma unroll
    for (int e = 0; e < 8; ++e)
        v1[e] = f2bf(W[(size_t)(k0 + e) * EE + col]);
    *(short8*)(bp + ((size_t)tile * 64 + lane) * 8) = *(const short8*)v1;
}

// 256 blocks x 1024 threads (1 block/CU, 16 waves). Block: 128 rows x 640 cols.
// Wave w: rg=w>>3 (64-row half), cg=w&7 (80 cols = 5 frags). acc[4][5].
// T3 2-phase: dbuf A+B, stage(kt+1) issued BEFORE compute(kt), ONE barrier/kt.
__global__ __launch_bounds__(1024, 4) void fused_mfma(
    const float* __restrict__ x, const unsigned short* __restrict__ bp,
    const float* __restrict__ bias, const float* __restrict__ cb,
    const float* __restrict__ gum, float* __restrict__ out,
    float* __restrict__ probs_acc)
{
    __shared__ unsigned short Bs[2][32 * EE];     // 2 x 40 KB
    __shared__ unsigned short As[2][BM * 32];     // 2 x 8 KB
    __shared__ float probs_blk[EE];
    __shared__ float pmax[8][BM];
    __shared__ float psum[8][BM];
    __shared__ int   pidx[8][BM];
    __shared__ int   fidx[BM][2];
    __shared__ float finv[BM][2];

    const int t    = threadIdx.x;
    const int lane = t & 63;
    const int w    = t >> 6;            // 0..15
    const int rg   = w >> 3;            // 64-row half
    const int cg   = w & 7;             // 80-col group
    const int n0   = blockIdx.x * BM;

    float4v acc[4][5];
    #pragma unroll
    for (int rf = 0; rf < 4; ++rf)
        #pragma unroll
        for (int ct = 0; ct < 5; ++ct)
            acc[rf][ct] = (float4v)0.f;

    // A staging: thread t stages one float4: row r0 = t>>3, k-quad kq0 = t&7
    const int r0 = t >> 3, kq0 = t & 7;
    const int abase = (r0 >> 4)*512 + ((r0 & 15) + ((kq0 >> 1) << 4))*8 + ((kq0 & 1) << 2);
    const float* xr = x + (size_t)(n0 + r0) * DD + kq0 * 4;

    auto writeA = [&](int bb, float4 v) {
        short4v s1;
        s1[0] = (short)f2bf(v.x); s1[1] = (short)f2bf(v.y);
        s1[2] = (short)f2bf(v.z); s1[3] = (short)f2bf(v.w);
        *(short4v*)&As[bb][abase] = s1;
    };
    // B staging: 2560 16B-slots per kt across 1024 threads
    auto stageB = [&](int bb, int kt) {
        const unsigned short* src = bp + (size_t)kt * (32 * EE);
        gload_lds16(src + (size_t)t * 8,          &Bs[bb][t * 8]);
        gload_lds16(src + (size_t)(t + 1024) * 8, &Bs[bb][(t + 1024) * 8]);
        if (t < 512)
            gload_lds16(src + (size_t)(t + 2048) * 8, &Bs[bb][(t + 2048) * 8]);
    };

    // prologue: stage kt=0 into buffer 0
    float4 pA = *(const float4*)(xr);
    stageB(0, 0);
    __syncthreads();              // vmcnt drain: Bs[0] staged, pA arrived
    writeA(0, pA);
    __syncthreads();              // As[0] visible

    int cur = 0;
    for (int kt = 0; kt < KT; ++kt) {
        const bool more = (kt + 1 < KT);
        if (more) {
            stageB(cur ^ 1, kt + 1);                        // async, overlaps compute
            pA = *(const float4*)(xr + (kt + 1) * 32);      // issue-early
        }
        short8 af[4];
        #pragma unroll
        for (int rf = 0; rf < 4; ++rf)
            af[rf] = *(const short8*)&As[cur][(rg*4 + rf)*512 + lane*8];
        #pragma unroll
        for (int ct = 0; ct < 5; ++ct) {
            short8 bf = *(const short8*)&Bs[cur][((cg*5 + ct)*64 + lane)*8];
            #pragma unroll
            for (int rf = 0; rf < 4; ++rf)
                acc[rf][ct] = __builtin_amdgcn_mfma_f32_16x16x32_bf16(af[rf], bf, acc[rf][ct], 0, 0, 0);
        }
        if (more) writeA(cur ^ 1, pA);                      // write-late
        __syncthreads();          // ONE barrier/kt: drains stage + A-write
        cur ^= 1;
    }

    // bias (zeros in this problem; kept faithful)
    {
        float bv[5];
        #pragma unroll
        for (int ct = 0; ct < 5; ++ct) bv[ct] = bias[cg*80 + ct*16 + (lane & 15)];
        #pragma unroll
        for (int rf = 0; rf < 4; ++rf)
            #pragma unroll
            for (int ct = 0; ct < 5; ++ct) {
                acc[rf][ct][0] += bv[ct]; acc[rf][ct][1] += bv[ct];
                acc[rf][ct][2] += bv[ct]; acc[rf][ct][3] += bv[ct];
            }
    }

    // ---- Phase A: gumbel-argmax partial + clean exp-sum partial ----
    const int g = cg >> 2;                         // 4 col-waves per group
    const int goff0 = (cg & 3)*80 + (lane & 15);   // col within group
    #pragma unroll
    for (int rf = 0; rf < 4; ++rf) {
        #pragma unroll
        for (int r = 0; r < 4; ++r) {
            const int rowA = rg*64 + rf*16 + ((lane >> 4) << 2) + r;
            const float* grow = gum + ((size_t)(n0 + rowA)*2 + g)*VV + goff0;
            float m1 = -1e30f; int bi = 0; float es = 0.f;
            #pragma unroll
            for (int ct = 0; ct < 5; ++ct) {
                float z  = acc[rf][ct][r];
                float zg = z + grow[ct*16];
                if (zg > m1) { m1 = zg; bi = goff0 + ct*16; }
                es += __expf(z);
            }
            #pragma unroll
            for (int off = 1; off < 16; off <<= 1) {
                float om = __shfl_xor(m1, off);
                int   ob = __shfl_xor(bi, off);
                if (om > m1 || (om == m1 && ob < bi)) { m1 = om; bi = ob; }
                es += __shfl_xor(es, off);
            }
            if ((lane & 15) == 0) {
                pmax[cg][rowA] = m1; pidx[cg][rowA] = bi; psum[cg][rowA] = es;
            }
        }
    }
    for (int c = t; c < EE; c += 1024) probs_blk[c] = 0.f;
    __syncthreads();

    // ---- Phase B: cross-wave combine (4 partials per row,group) ----
    if (t < 256) {
        const int row = t & 127, gg = t >> 7;
        float m1 = -1e30f; int bi = 0x7fffffff; float s = 0.f;
        #pragma unroll
        for (int c = 0; c < 4; ++c) {
            const float om = pmax[gg*4 + c][row];
            const int   ob = pidx[gg*4 + c][row];
            if (om > m1 || (om == m1 && ob < bi)) { m1 = om; bi = ob; }
            s += psum[gg*4 + c][row];
        }
        fidx[row][gg] = bi;
        finv[row][gg] = 1.f / s;
    }
    __syncthreads();

    // ---- Phase C: probs accumulation ----
    float pacc[5];
    #pragma unroll
    for (int ct = 0; ct < 5; ++ct) pacc[ct] = 0.f;
    #pragma unroll
    for (int rf = 0; rf < 4; ++rf) {
        #pragma unroll
        for (int r = 0; r < 4; ++r) {
            const int rowA = rg*64 + rf*16 + ((lane >> 4) << 2) + r;
            const float inv = finv[rowA][g];
            #pragma unroll
            for (int ct = 0; ct < 5; ++ct)
                pacc[ct] += __expf(acc[rf][ct][r]) * inv;
        }
    }
    #pragma unroll
    for (int off = 16; off < 64; off <<= 1)
        #pragma unroll
        for (int ct = 0; ct < 5; ++ct)
            pacc[ct] += __shfl_xor(pacc[ct], off);
    if (lane < 16) {
        #pragma unroll
        for (int ct = 0; ct < 5; ++ct)
            atomicAdd(&probs_blk[cg*80 + ct*16 + lane], pacc[ct]);
    }
    __syncthreads();

    for (int c = t; c < EE; c += 1024)
        atomicAdd(&probs_acc[c], probs_blk[c]);

    // ---- output: codebook gather (row-uniform idx, coalesced) ----
    for (int i = t; i < BM*256; i += 1024) {
        const int row = i >> 8, f4 = i & 255;
        const int gg  = f4 >> 7;
        const int idx = fidx[row][gg];
        const float4 v = *(const float4*)&cb[((size_t)gg*VV + idx)*512 + (size_t)(f4 & 127)*4];
        *(float4*)&out[(size_t)(n0 + row)*DD + (size_t)f4*4] = v;
    }
}

__global__ void perp_kernel(const float* __restrict__ probs_acc,
                            float* __restrict__ outp)
{
    __shared__ float s0[4], s1[4];
    int t = threadIdx.x;   // 256
    float p0 = 0.f, p1 = 0.f;
    for (int c = t; c < EE; c += 256) {
        float a = probs_acc[c] * (1.0f / NROWS);
        float v = a * logf(a + 1e-7f);
        if (c < VV) p0 += v; else p1 += v;
    }
    #pragma unroll
    for (int off = 1; off < 64; off <<= 1) {
        p0 += __shfl_xor(p0, off);
        p1 += __shfl_xor(p1, off);
    }
    if ((t & 63) == 0) { s0[t >> 6] = p0; s1[t >> 6] = p1; }
    __syncthreads();
    if (t == 0) {
        float a0 = s0[0] + s0[1] + s0[2] + s0[3];
        float a1 = s1[0] + s1[1] + s1[2] + s1[3];
        outp[0] = 0.5f * (expf(-a0) + expf(-a1));
    }
}

extern "C" void kernel_launch(void* const* d_in, const int* in_sizes, int n_in,
                              void* d_out, int out_size, void* d_ws, size_t ws_size,
                              hipStream_t stream)
{
    const float* x   = (const float*)d_in[0];
    const float* W   = (const float*)d_in[1];
    const float* b   = (const float*)d_in[2];
    const float* cb  = (const float*)d_in[3];
    const float* gum = (const float*)d_in[4];
    float* out = (float*)d_out;

    unsigned short* bp = (unsigned short*)d_ws;                  // 1.31 MB packed W
    float* probs_acc = (float*)((char*)d_ws + (size_t)DD*EE*2);

    hipMemsetAsync(probs_acc, 0, EE * sizeof(float), stream);
    pack_w<<<320, 256, 0, stream>>>(W, bp);
    fused_mfma<<<NROWS / BM, 1024, 0, stream>>>(x, bp, b, cb, gum, out, probs_acc);
    perp_kernel<<<1, 256, 0, stream>>>(probs_acc, out + (out_size - 1));
}

// Round 7
// 128.775 us; speedup vs baseline: 2.1598x; 1.0142x over previous
//
#include <hip/hip_runtime.h>
#include <hip/hip_bf16.h>
#include <math.h>

#define NROWS 32768
#define DD    1024
#define EE    640
#define VV    320
#define BM    128
#define KT    32      // DD/32
#define CTN   40      // EE/16

typedef __attribute__((ext_vector_type(8))) short short8;
typedef __attribute__((ext_vector_type(4))) short short4v;
typedef __attribute__((ext_vector_type(4))) float float4v;

static __device__ __forceinline__ unsigned short f2bf(float f) {
    unsigned int u = __float_as_uint(f);
    return (unsigned short)((u + 0x7fffu + ((u >> 16) & 1u)) >> 16); // RNE
}

static __device__ __forceinline__ void gload_lds16(const void* g, void* l) {
    __builtin_amdgcn_global_load_lds(
        (const __attribute__((address_space(1))) unsigned int*)g,
        (__attribute__((address_space(3))) unsigned int*)l, 16, 0, 0);
}

// Pack W [K=1024][N=640] fp32 -> bf16, MFMA fragment layout:
// frag(kt, ct): lane l, elem e  <=  W[kt*32 + (l>>4)*8 + e][ct*16 + (l&15)]
__global__ void pack_w(const float* __restrict__ W, unsigned short* __restrict__ bp)
{
    const int t = threadIdx.x;
    const int tile = blockIdx.x * 4 + (t >> 6);   // 0..1279 = kt*40+ct
    const int lane = t & 63;
    const int kt = tile / CTN, ct = tile % CTN;
    const int k0 = kt * 32 + (lane >> 4) * 8;
    const int col = ct * 16 + (lane & 15);
    unsigned short v1[8];
    #pragma unroll
    for (int e = 0; e < 8; ++e)
        v1[e] = f2bf(W[(size_t)(k0 + e) * EE + col]);
    *(short8*)(bp + ((size_t)tile * 64 + lane) * 8) = *(const short8*)v1;
}

// 256 blocks x 1024 threads (1 block/CU, 16 waves). Block: 128 rows x 640 cols.
// Wave w: rg=w>>3 (64-row half), cg=w&7 (80 cols = 5 frags). acc[4][5].
// T4 counted-vmcnt pipeline: B = 3-deep LDS ring staged via global_load_lds,
// A = dbuf LDS staged via reg (x load 2 tiles ahead). Raw s_barrier + explicit
// s_waitcnt vmcnt(4) -> staging loads stay in flight ACROSS barriers.
__global__ __launch_bounds__(1024, 4) void fused_mfma(
    const float* __restrict__ x, const unsigned short* __restrict__ bp,
    const float* __restrict__ bias, const float* __restrict__ cb,
    const float* __restrict__ gum, float* __restrict__ out,
    float* __restrict__ probs_acc)
{
    __shared__ unsigned short Bs[3][32 * EE];     // 3 x 40 KB ring
    __shared__ unsigned short As[2][BM * 32];     // 2 x 8 KB
    __shared__ float probs_blk[EE];
    __shared__ float pmax[8][BM];
    __shared__ float psum[8][BM];
    __shared__ int   pidx[8][BM];
    __shared__ int   fidx[BM][2];
    __shared__ float finv[BM][2];

    const int t    = threadIdx.x;
    const int lane = t & 63;
    const int w    = t >> 6;            // 0..15
    const int rg   = w >> 3;            // 64-row half
    const int cg   = w & 7;             // 80-col group
    const int n0   = blockIdx.x * BM;

    float4v acc[4][5];
    #pragma unroll
    for (int rf = 0; rf < 4; ++rf)
        #pragma unroll
        for (int ct = 0; ct < 5; ++ct)
            acc[rf][ct] = (float4v)0.f;

    // A staging: thread t stages one float4: row r0 = t>>3, k-quad kq0 = t&7
    const int r0 = t >> 3, kq0 = t & 7;
    const int abase = (r0 >> 4)*512 + ((r0 & 15) + ((kq0 >> 1) << 4))*8 + ((kq0 & 1) << 2);
    const float* xr = x + (size_t)(n0 + r0) * DD + kq0 * 4;

    auto writeA = [&](int bb, float4 v) {
        short4v s1;
        s1[0] = (short)f2bf(v.x); s1[1] = (short)f2bf(v.y);
        s1[2] = (short)f2bf(v.z); s1[3] = (short)f2bf(v.w);
        *(short4v*)&As[bb][abase] = s1;
    };
    // B staging: 2560 16B-slots; uniform 3 gload_lds/thread (512 duplicate slots)
    const int q0 = t, q1 = t + 1024, q2 = (t < 512) ? t + 2048 : t + 1536;
    auto stageB = [&](int bb, int kt) {
        const unsigned short* src = bp + (size_t)kt * (32 * EE);
        gload_lds16(src + (size_t)q0 * 8, &Bs[bb][q0 * 8]);
        gload_lds16(src + (size_t)q1 * 8, &Bs[bb][q1 * 8]);
        gload_lds16(src + (size_t)q2 * 8, &Bs[bb][q2 * 8]);
    };

    // Per-iteration VMEM issue = 4 ops/thread (3 B gloads + 1 x load).
    // vmcnt(4) at top of iter i  => tile-i staging fully landed,
    // tile-(i+1)'s 4 ops may remain in flight across the barrier.
    auto kbody = [&](int i, int b0, int bstg, float4& curA, float4& nxtA) {
        asm volatile("s_waitcnt vmcnt(4) lgkmcnt(0)" ::: "memory");
        __builtin_amdgcn_s_barrier();
        __builtin_amdgcn_sched_barrier(0);
        if (i + 2 < KT) {
            stageB(bstg, i + 2);
            nxtA = *(const float4*)(xr + (size_t)(i + 2) * 32);
        }
        __builtin_amdgcn_sched_barrier(0);
        short8 af[4];
        #pragma unroll
        for (int rf = 0; rf < 4; ++rf)
            af[rf] = *(const short8*)&As[i & 1][(rg*4 + rf)*512 + lane*8];
        #pragma unroll
        for (int ct = 0; ct < 5; ++ct) {
            short8 bf = *(const short8*)&Bs[b0][((cg*5 + ct)*64 + lane)*8];
            #pragma unroll
            for (int rf = 0; rf < 4; ++rf)
                acc[rf][ct] = __builtin_amdgcn_mfma_f32_16x16x32_bf16(af[rf], bf, acc[rf][ct], 0, 0, 0);
        }
        __builtin_amdgcn_sched_barrier(0);
        if (i + 1 < KT) writeA((i + 1) & 1, curA);  // compiler auto-waits curA's load
    };

    // prologue: queue order B(0),x(0),B(1),x(1); writeA(0) auto-waits to vmcnt(4)
    float4 pA0, pA1;
    {
        stageB(0, 0);
        float4 a00 = *(const float4*)(xr);
        stageB(1, 1);
        pA0 = *(const float4*)(xr + 32);
        __builtin_amdgcn_sched_barrier(0);
        writeA(0, a00);
    }

    int bc = 0;   // ring buffer holding tile i (i%3)
    for (int i = 0; i < KT; i += 2) {
        const int b1 = (bc + 1 > 2) ? 0 : bc + 1;
        const int b2 = (bc + 2 > 2) ? bc - 1 : bc + 2;
        kbody(i,     bc, b2, pA0, pA1);
        kbody(i + 1, b1, bc, pA1, pA0);
        bc = b2;
    }

    // bias (zeros in this problem; kept faithful)
    {
        float bv[5];
        #pragma unroll
        for (int ct = 0; ct < 5; ++ct) bv[ct] = bias[cg*80 + ct*16 + (lane & 15)];
        #pragma unroll
        for (int rf = 0; rf < 4; ++rf)
            #pragma unroll
            for (int ct = 0; ct < 5; ++ct) {
                acc[rf][ct][0] += bv[ct]; acc[rf][ct][1] += bv[ct];
                acc[rf][ct][2] += bv[ct]; acc[rf][ct][3] += bv[ct];
            }
    }

    // ---- Phase A: gumbel-argmax partial + clean exp-sum partial ----
    const int g = cg >> 2;                         // 4 col-waves per group
    const int goff0 = (cg & 3)*80 + (lane & 15);   // col within group
    #pragma unroll
    for (int rf = 0; rf < 4; ++rf) {
        #pragma unroll
        for (int r = 0; r < 4; ++r) {
            const int rowA = rg*64 + rf*16 + ((lane >> 4) << 2) + r;
            const float* grow = gum + ((size_t)(n0 + rowA)*2 + g)*VV + goff0;
            float m1 = -1e30f; int bi = 0; float es = 0.f;
            #pragma unroll
            for (int ct = 0; ct < 5; ++ct) {
                float z  = acc[rf][ct][r];
                float zg = z + grow[ct*16];
                if (zg > m1) { m1 = zg; bi = goff0 + ct*16; }
                es += __expf(z);
            }
            #pragma unroll
            for (int off = 1; off < 16; off <<= 1) {
                float om = __shfl_xor(m1, off);
                int   ob = __shfl_xor(bi, off);
                if (om > m1 || (om == m1 && ob < bi)) { m1 = om; bi = ob; }
                es += __shfl_xor(es, off);
            }
            if ((lane & 15) == 0) {
                pmax[cg][rowA] = m1; pidx[cg][rowA] = bi; psum[cg][rowA] = es;
            }
        }
    }
    for (int c = t; c < EE; c += 1024) probs_blk[c] = 0.f;
    __syncthreads();

    // ---- Phase B: cross-wave combine (4 partials per row,group) ----
    if (t < 256) {
        const int row = t & 127, gg = t >> 7;
        float m1 = -1e30f; int bi = 0x7fffffff; float s = 0.f;
        #pragma unroll
        for (int c = 0; c < 4; ++c) {
            const float om = pmax[gg*4 + c][row];
            const int   ob = pidx[gg*4 + c][row];
            if (om > m1 || (om == m1 && ob < bi)) { m1 = om; bi = ob; }
            s += psum[gg*4 + c][row];
        }
        fidx[row][gg] = bi;
        finv[row][gg] = 1.f / s;
    }
    __syncthreads();

    // ---- Phase C: probs accumulation ----
    float pacc[5];
    #pragma unroll
    for (int ct = 0; ct < 5; ++ct) pacc[ct] = 0.f;
    #pragma unroll
    for (int rf = 0; rf < 4; ++rf) {
        #pragma unroll
        for (int r = 0; r < 4; ++r) {
            const int rowA = rg*64 + rf*16 + ((lane >> 4) << 2) + r;
            const float inv = finv[rowA][g];
            #pragma unroll
            for (int ct = 0; ct < 5; ++ct)
                pacc[ct] += __expf(acc[rf][ct][r]) * inv;
        }
    }
    #pragma unroll
    for (int off = 16; off < 64; off <<= 1)
        #pragma unroll
        for (int ct = 0; ct < 5; ++ct)
            pacc[ct] += __shfl_xor(pacc[ct], off);
    if (lane < 16) {
        #pragma unroll
        for (int ct = 0; ct < 5; ++ct)
            atomicAdd(&probs_blk[cg*80 + ct*16 + lane], pacc[ct]);
    }
    __syncthreads();

    for (int c = t; c < EE; c += 1024)
        atomicAdd(&probs_acc[c], probs_blk[c]);

    // ---- output: codebook gather (row-uniform idx, coalesced) ----
    for (int i = t; i < BM*256; i += 1024) {
        const int row = i >> 8, f4 = i & 255;
        const int gg  = f4 >> 7;
        const int idx = fidx[row][gg];
        const float4 v = *(const float4*)&cb[((size_t)gg*VV + idx)*512 + (size_t)(f4 & 127)*4];
        *(float4*)&out[(size_t)(n0 + row)*DD + (size_t)f4*4] = v;
    }
}

__global__ void perp_kernel(const float* __restrict__ probs_acc,
                            float* __restrict__ outp)
{
    __shared__ float s0[4], s1[4];
    int t = threadIdx.x;   // 256
    float p0 = 0.f, p1 = 0.f;
    for (int c = t; c < EE; c += 256) {
        float a = probs_acc[c] * (1.0f / NROWS);
        float v = a * logf(a + 1e-7f);
        if (c < VV) p0 += v; else p1 += v;
    }
    #pragma unroll
    for (int off = 1; off < 64; off <<= 1) {
        p0 += __shfl_xor(p0, off);
        p1 += __shfl_xor(p1, off);
    }
    if ((t & 63) == 0) { s0[t >> 6] = p0; s1[t >> 6] = p1; }
    __syncthreads();
    if (t == 0) {
        float a0 = s0[0] + s0[1] + s0[2] + s0[3];
        float a1 = s1[0] + s1[1] + s1[2] + s1[3];
        outp[0] = 0.5f * (expf(-a0) + expf(-a1));
    }
}

extern "C" void kernel_launch(void* const* d_in, const int* in_sizes, int n_in,
                              void* d_out, int out_size, void* d_ws, size_t ws_size,
                              hipStream_t stream)
{
    const float* x   = (const float*)d_in[0];
    const float* W   = (const float*)d_in[1];
    const float* b   = (const float*)d_in[2];
    const float* cb  = (const float*)d_in[3];
    const float* gum = (const float*)d_in[4];
    float* out = (float*)d_out;

    unsigned short* bp = (unsigned short*)d_ws;                  // 1.31 MB packed W
    float* probs_acc = (float*)((char*)d_ws + (size_t)DD*EE*2);

    hipMemsetAsync(probs_acc, 0, EE * sizeof(float), stream);
    pack_w<<<320, 256, 0, stream>>>(W, bp);
    fused_mfma<<<NROWS / BM, 1024, 0, stream>>>(x, bp, b, cb, gum, out, probs_acc);
    perp_kernel<<<1, 256, 0, stream>>>(probs_acc, out + (out_size - 1));
}

// Round 8
// 128.635 us; speedup vs baseline: 2.1621x; 1.0011x over previous
//
#include <hip/hip_runtime.h>
#include <hip/hip_bf16.h>
#include <math.h>

#define NROWS 32768
#define DD    1024
#define EE    640
#define VV    320
#define BM    128
#define KT    32      // DD/32
#define CTN   40      // EE/16

typedef __attribute__((ext_vector_type(8))) short short8;
typedef __attribute__((ext_vector_type(4))) short short4v;
typedef __attribute__((ext_vector_type(4))) float float4v;

static __device__ __forceinline__ unsigned short f2bf(float f) {
    unsigned int u = __float_as_uint(f);
    return (unsigned short)((u + 0x7fffu + ((u >> 16) & 1u)) >> 16); // RNE
}

static __device__ __forceinline__ void gload_lds16(const void* g, void* l) {
    __builtin_amdgcn_global_load_lds(
        (const __attribute__((address_space(1))) unsigned int*)g,
        (__attribute__((address_space(3))) unsigned int*)l, 16, 0, 0);
}

// Pack W [K=1024][N=640] fp32 -> bf16, MFMA fragment layout:
// frag(kt, ct): lane l, elem e  <=  W[kt*32 + (l>>4)*8 + e][ct*16 + (l&15)]
__global__ void pack_w(const float* __restrict__ W, unsigned short* __restrict__ bp)
{
    const int t = threadIdx.x;
    const int tile = blockIdx.x * 4 + (t >> 6);   // 0..1279 = kt*40+ct
    const int lane = t & 63;
    const int kt = tile / CTN, ct = tile % CTN;
    const int k0 = kt * 32 + (lane >> 4) * 8;
    const int col = ct * 16 + (lane & 15);
    unsigned short v1[8];
    #pragma unroll
    for (int e = 0; e < 8; ++e)
        v1[e] = f2bf(W[(size_t)(k0 + e) * EE + col]);
    *(short8*)(bp + ((size_t)tile * 64 + lane) * 8) = *(const short8*)v1;
}

// K1: 256 blocks x 1024 threads. Block: 128 rows x 640 cols.
// Wave w: rg=w>>3 (64-row half), cg=w&7 (80 cols = 5 frags). acc[4][5].
// Writes fidx[N][2] (argmax) + probs_acc atomics. NO out-write (K2 does it).
__global__ __launch_bounds__(1024, 4) void logits_kernel(
    const float* __restrict__ x, const unsigned short* __restrict__ bp,
    const float* __restrict__ bias, const float* __restrict__ gum,
    int* __restrict__ gfidx, float* __restrict__ probs_acc)
{
    __shared__ unsigned short Bs[3][32 * EE];     // 3 x 40 KB ring
    __shared__ unsigned short As[2][BM * 32];     // 2 x 8 KB
    __shared__ float probs_blk[EE];
    __shared__ float pmax[8][BM];
    __shared__ float psum[8][BM];
    __shared__ int   pidx[8][BM];
    __shared__ float finv[BM][2];

    const int t    = threadIdx.x;
    const int lane = t & 63;
    const int w    = t >> 6;            // 0..15
    const int rg   = w >> 3;            // 64-row half
    const int cg   = w & 7;             // 80-col group
    const int n0   = blockIdx.x * BM;

    float4v acc[4][5];
    #pragma unroll
    for (int rf = 0; rf < 4; ++rf)
        #pragma unroll
        for (int ct = 0; ct < 5; ++ct)
            acc[rf][ct] = (float4v)0.f;

    // A staging: thread t stages one float4: row r0 = t>>3, k-quad kq0 = t&7
    const int r0 = t >> 3, kq0 = t & 7;
    const int abase = (r0 >> 4)*512 + ((r0 & 15) + ((kq0 >> 1) << 4))*8 + ((kq0 & 1) << 2);
    const float* xr = x + (size_t)(n0 + r0) * DD + kq0 * 4;

    auto writeA = [&](int bb, float4 v) {
        short4v s1;
        s1[0] = (short)f2bf(v.x); s1[1] = (short)f2bf(v.y);
        s1[2] = (short)f2bf(v.z); s1[3] = (short)f2bf(v.w);
        *(short4v*)&As[bb][abase] = s1;
    };
    // B staging: 2560 16B-slots; uniform 3 gload_lds/thread (512 duplicate slots)
    const int q0 = t, q1 = t + 1024, q2 = (t < 512) ? t + 2048 : t + 1536;
    auto stageB = [&](int bb, int kt) {
        const unsigned short* src = bp + (size_t)kt * (32 * EE);
        gload_lds16(src + (size_t)q0 * 8, &Bs[bb][q0 * 8]);
        gload_lds16(src + (size_t)q1 * 8, &Bs[bb][q1 * 8]);
        gload_lds16(src + (size_t)q2 * 8, &Bs[bb][q2 * 8]);
    };

    // Per-iteration VMEM issue = 4 ops/thread (3 B gloads + 1 x load).
    auto kbody = [&](int i, int b0, int bstg, float4& curA, float4& nxtA) {
        asm volatile("s_waitcnt vmcnt(4) lgkmcnt(0)" ::: "memory");
        __builtin_amdgcn_s_barrier();
        __builtin_amdgcn_sched_barrier(0);
        if (i + 2 < KT) {
            stageB(bstg, i + 2);
            nxtA = *(const float4*)(xr + (size_t)(i + 2) * 32);
        }
        __builtin_amdgcn_sched_barrier(0);
        short8 af[4];
        #pragma unroll
        for (int rf = 0; rf < 4; ++rf)
            af[rf] = *(const short8*)&As[i & 1][(rg*4 + rf)*512 + lane*8];
        #pragma unroll
        for (int ct = 0; ct < 5; ++ct) {
            short8 bf = *(const short8*)&Bs[b0][((cg*5 + ct)*64 + lane)*8];
            #pragma unroll
            for (int rf = 0; rf < 4; ++rf)
                acc[rf][ct] = __builtin_amdgcn_mfma_f32_16x16x32_bf16(af[rf], bf, acc[rf][ct], 0, 0, 0);
        }
        __builtin_amdgcn_sched_barrier(0);
        if (i + 1 < KT) writeA((i + 1) & 1, curA);  // compiler auto-waits curA's load
    };

    // prologue
    float4 pA0, pA1;
    {
        stageB(0, 0);
        float4 a00 = *(const float4*)(xr);
        stageB(1, 1);
        pA0 = *(const float4*)(xr + 32);
        __builtin_amdgcn_sched_barrier(0);
        writeA(0, a00);
    }

    int bc = 0;   // ring buffer holding tile i (i%3)
    for (int i = 0; i < KT; i += 2) {
        const int b1 = (bc + 1 > 2) ? 0 : bc + 1;
        const int b2 = (bc + 2 > 2) ? bc - 1 : bc + 2;
        kbody(i,     bc, b2, pA0, pA1);
        kbody(i + 1, b1, bc, pA1, pA0);
        bc = b2;
    }

    // bias (zeros in this problem; kept faithful)
    {
        float bv[5];
        #pragma unroll
        for (int ct = 0; ct < 5; ++ct) bv[ct] = bias[cg*80 + ct*16 + (lane & 15)];
        #pragma unroll
        for (int rf = 0; rf < 4; ++rf)
            #pragma unroll
            for (int ct = 0; ct < 5; ++ct) {
                acc[rf][ct][0] += bv[ct]; acc[rf][ct][1] += bv[ct];
                acc[rf][ct][2] += bv[ct]; acc[rf][ct][3] += bv[ct];
            }
    }

    // ---- Phase A: gumbel-argmax partial + clean exp-sum partial ----
    const int g = cg >> 2;                         // 4 col-waves per group
    const int goff0 = (cg & 3)*80 + (lane & 15);   // col within group
    #pragma unroll
    for (int rf = 0; rf < 4; ++rf) {
        #pragma unroll
        for (int r = 0; r < 4; ++r) {
            const int rowA = rg*64 + rf*16 + ((lane >> 4) << 2) + r;
            const float* grow = gum + ((size_t)(n0 + rowA)*2 + g)*VV + goff0;
            float m1 = -1e30f; int bi = 0; float es = 0.f;
            #pragma unroll
            for (int ct = 0; ct < 5; ++ct) {
                float z  = acc[rf][ct][r];
                float zg = z + grow[ct*16];
                if (zg > m1) { m1 = zg; bi = goff0 + ct*16; }
                es += __expf(z);
            }
            #pragma unroll
            for (int off = 1; off < 16; off <<= 1) {
                float om = __shfl_xor(m1, off);
                int   ob = __shfl_xor(bi, off);
                if (om > m1 || (om == m1 && ob < bi)) { m1 = om; bi = ob; }
                es += __shfl_xor(es, off);
            }
            if ((lane & 15) == 0) {
                pmax[cg][rowA] = m1; pidx[cg][rowA] = bi; psum[cg][rowA] = es;
            }
        }
    }
    for (int c = t; c < EE; c += 1024) probs_blk[c] = 0.f;
    __syncthreads();

    // ---- Phase B: combine 4 partials per (row,group); write argmax to global ----
    if (t < 256) {
        const int row = t & 127, gg = t >> 7;
        float m1 = -1e30f; int bi = 0x7fffffff; float s = 0.f;
        #pragma unroll
        for (int c = 0; c < 4; ++c) {
            const float om = pmax[gg*4 + c][row];
            const int   ob = pidx[gg*4 + c][row];
            if (om > m1 || (om == m1 && ob < bi)) { m1 = om; bi = ob; }
            s += psum[gg*4 + c][row];
        }
        gfidx[(size_t)(n0 + row)*2 + gg] = bi;
        finv[row][gg] = 1.f / s;
    }
    __syncthreads();

    // ---- Phase C: probs accumulation ----
    float pacc[5];
    #pragma unroll
    for (int ct = 0; ct < 5; ++ct) pacc[ct] = 0.f;
    #pragma unroll
    for (int rf = 0; rf < 4; ++rf) {
        #pragma unroll
        for (int r = 0; r < 4; ++r) {
            const int rowA = rg*64 + rf*16 + ((lane >> 4) << 2) + r;
            const float inv = finv[rowA][g];
            #pragma unroll
            for (int ct = 0; ct < 5; ++ct)
                pacc[ct] += __expf(acc[rf][ct][r]) * inv;
        }
    }
    #pragma unroll
    for (int off = 16; off < 64; off <<= 1)
        #pragma unroll
        for (int ct = 0; ct < 5; ++ct)
            pacc[ct] += __shfl_xor(pacc[ct], off);
    if (lane < 16) {
        #pragma unroll
        for (int ct = 0; ct < 5; ++ct)
            atomicAdd(&probs_blk[cg*80 + ct*16 + lane], pacc[ct]);
    }
    __syncthreads();

    for (int c = t; c < EE; c += 1024)
        atomicAdd(&probs_acc[c], probs_blk[c]);
}

// K2: 4096 blocks x 256 threads; block = 8 rows. Pure streaming out-write.
// Block 0 additionally computes perplexity (probs_acc complete after K1).
__global__ __launch_bounds__(256) void gather_kernel(
    const float* __restrict__ cb, const int* __restrict__ gfidx,
    const float* __restrict__ probs_acc, float* __restrict__ out, int out_size)
{
    __shared__ int sidx[8][2];
    __shared__ float s0[4], s1[4];
    const int t  = threadIdx.x;
    const int r0 = blockIdx.x * 8;
    if (t < 16) sidx[t >> 1][t & 1] = gfidx[(size_t)(r0 + (t >> 1)) * 2 + (t & 1)];
    __syncthreads();
    const int gg = t >> 7;             // group half
    const int f4 = t & 127;            // float4 index within half
    #pragma unroll
    for (int r = 0; r < 8; ++r) {
        const int idx = sidx[r][gg];
        const float4 v = *(const float4*)&cb[((size_t)gg*VV + idx)*512 + (size_t)f4*4];
        *(float4*)&out[(size_t)(r0 + r)*DD + (size_t)t*4] = v;
    }
    if (blockIdx.x == 0) {
        float p0 = 0.f, p1 = 0.f;
        for (int c = t; c < EE; c += 256) {
            float a = probs_acc[c] * (1.0f / NROWS);
            float v = a * logf(a + 1e-7f);
            if (c < VV) p0 += v; else p1 += v;
        }
        #pragma unroll
        for (int off = 1; off < 64; off <<= 1) {
            p0 += __shfl_xor(p0, off);
            p1 += __shfl_xor(p1, off);
        }
        if ((t & 63) == 0) { s0[t >> 6] = p0; s1[t >> 6] = p1; }
        __syncthreads();
        if (t == 0) {
            float a0 = s0[0] + s0[1] + s0[2] + s0[3];
            float a1 = s1[0] + s1[1] + s1[2] + s1[3];
            out[out_size - 1] = 0.5f * (expf(-a0) + expf(-a1));
        }
    }
}

extern "C" void kernel_launch(void* const* d_in, const int* in_sizes, int n_in,
                              void* d_out, int out_size, void* d_ws, size_t ws_size,
                              hipStream_t stream)
{
    const float* x   = (const float*)d_in[0];
    const float* W   = (const float*)d_in[1];
    const float* b   = (const float*)d_in[2];
    const float* cb  = (const float*)d_in[3];
    const float* gum = (const float*)d_in[4];
    float* out = (float*)d_out;

    unsigned short* bp = (unsigned short*)d_ws;                  // 1.31 MB packed W
    float* probs_acc = (float*)((char*)d_ws + (size_t)DD*EE*2);
    int*   gfidx     = (int*)((char*)d_ws + (size_t)DD*EE*2 + 4096);

    hipMemsetAsync(probs_acc, 0, EE * sizeof(float), stream);
    pack_w<<<320, 256, 0, stream>>>(W, bp);
    logits_kernel<<<NROWS / BM, 1024, 0, stream>>>(x, bp, b, gum, gfidx, probs_acc);
    gather_kernel<<<NROWS / 8, 256, 0, stream>>>(cb, gfidx, probs_acc, out, out_size);
}